// Round 1
// 654.710 us; speedup vs baseline: 1.3600x; 1.3600x over previous
//
#include <hip/hip_runtime.h>

// cheb_conv_aagcn: B=8,K=3,N=2048,F_IN=16,F_OUT=64,T=12
// out[b,n,o,t] = relu( sum_k (1/Z_k[n]) sum_m exp(S[b,k,m,n]) cheb_k[m,n] x[b,m,:] @ Theta_k )
// cheb0=I (diagonal pick), cheb1=L=diag(deg)-adj, cheb2=2L*L-I (elementwise).
//
// v2 changes vs v1 (spill-elimination round):
//  - k_main: S chunk staged via global_load_lds into a single raw LDS buffer
//    (no sv[] registers -> no scratch spills, which were ~400MB of HBM writes)
//  - 256-thread blocks (4 waves), acc[4][3] per thread, adj prefetched to regs
//  - XCD-aware block swizzle: each XCD owns 4 n-tiles (adj/xT become L2-hot)
//  - diag handling hoisted out of hot pack loop (only 1 chunk/block can hit it)
//  - k_z0 vectorized (float4) with 2 row-halves per (tile,b)

#define NB 8
#define NN 2048
#define FT 192
#define BN 64
#define BM 64
#define LBM 72  // Pt row stride in bf16: 144B (16B-aligned)

typedef __attribute__((ext_vector_type(8))) short short8;
typedef __attribute__((ext_vector_type(4))) float f32x4;

__device__ __forceinline__ unsigned short bf16_rne(float f) {
  unsigned u = __float_as_uint(f);
  u += 0x7FFFu + ((u >> 16) & 1u);
  return (unsigned short)(u >> 16);
}

__device__ __forceinline__ void gload_lds16(const float* g, float* l) {
  __builtin_amdgcn_global_load_lds(
      (const __attribute__((address_space(1))) void*)g,
      (__attribute__((address_space(3))) void*)l, 16, 0, 0);
}

__global__ __launch_bounds__(256) void k_deg(const float* __restrict__ adj,
                                             float* __restrict__ deg) {
  const int row = blockIdx.x;
  const float* r = adj + (size_t)row * NN;
  float s = 0.f;
  for (int j = threadIdx.x; j < NN; j += 256) s += r[j];
  for (int off = 32; off; off >>= 1) s += __shfl_down(s, off, 64);
  __shared__ float ls[4];
  if ((threadIdx.x & 63) == 0) ls[threadIdx.x >> 6] = s;
  __syncthreads();
  if (threadIdx.x == 0) deg[row] = ls[0] + ls[1] + ls[2] + ls[3];
}

// grid (64, 8), block 192 (thread = ft). x[b][m][ft] -> xT[b][ft][m] bf16.
__global__ __launch_bounds__(192) void k_xt(const float* __restrict__ x,
                                            unsigned short* __restrict__ xT) {
  const int b = blockIdx.y, m0 = blockIdx.x * 32, ft = threadIdx.x;
  const float* src = x + (size_t)b * NN * FT + ft;
  uint4* dst = (uint4*)(xT + ((size_t)b * FT + ft) * NN + m0);
#pragma unroll
  for (int g = 0; g < 4; ++g) {
    unsigned u[4];
#pragma unroll
    for (int j = 0; j < 4; ++j) {
      float lo = src[(size_t)(m0 + g * 8 + 2 * j) * FT];
      float hi = src[(size_t)(m0 + g * 8 + 2 * j + 1) * FT];
      u[j] = (unsigned)bf16_rne(lo) | ((unsigned)bf16_rne(hi) << 16);
    }
    dst[g] = make_uint4(u[0], u[1], u[2], u[3]);
  }
}

// grid (32, NB, 2), block 256. Z0 partials over m-halves + diag exp capture.
// Vectorized float4 loads: thread (rg=t>>4, n4=(t&15)*4) walks rows rg, rg+16, ...
__global__ __launch_bounds__(256) void k_z0(const float* __restrict__ Sall,
                                            float* __restrict__ z0P,
                                            float* __restrict__ diagE) {
  __shared__ float zs[16][64];
  const int n0 = blockIdx.x * 64, b = blockIdx.y, half = blockIdx.z;
  const int t = threadIdx.x, n4 = (t & 15) * 4, rg = t >> 4;
  const float* S0 = Sall + (size_t)b * 3 * NN * NN;
  float z0 = 0.f, z1 = 0.f, z2 = 0.f, z3 = 0.f;
  const int mstart = half * 1024;
#pragma unroll 4
  for (int mm = rg; mm < 1024; mm += 16) {
    const int m = mstart + mm;
    const float4 v = *(const float4*)(S0 + (size_t)m * NN + n0 + n4);
    const float e0 = __expf(v.x), e1 = __expf(v.y), e2 = __expf(v.z),
                e3 = __expf(v.w);
    z0 += e0; z1 += e1; z2 += e2; z3 += e3;
    const int d = m - (n0 + n4);
    if (d >= 0 && d < 4) {
      const float ee[4] = {e0, e1, e2, e3};
      diagE[b * NN + m] = ee[d];
    }
  }
  zs[rg][n4 + 0] = z0;
  zs[rg][n4 + 1] = z1;
  zs[rg][n4 + 2] = z2;
  zs[rg][n4 + 3] = z3;
  __syncthreads();
  if (t < 64) {
    float s = 0.f;
#pragma unroll
    for (int g = 0; g < 16; ++g) s += zs[g][t];
    z0P[((size_t)b * 2 + half) * NN + n0 + t] = s;
  }
}

// pack one 64x64 chunk: raw S (LDS) + adj (regs) -> exp/cheb -> bf16 Pt.
// Thread (pmg=t>>4, pn4=(t&15)*4) owns rows pmg*4..+3, cols pn4..+3 --
// exactly the rows its own wave staged via global_load_lds.
template <bool ISK1>
__device__ __forceinline__ void pack_chunk(const float* SrawSh,
                                           const float4 av[4],
                                           const float* __restrict__ deg,
                                           unsigned short* PtDst, float zp[4],
                                           const int pmg, const int pn4,
                                           const bool dchunk, const int n0) {
  unsigned short pk[4][4];
#pragma unroll
  for (int r = 0; r < 4; ++r) {
    const float4 s = *(const float4*)&SrawSh[(pmg * 4 + r) * BN + pn4];
    const float se[4] = {s.x, s.y, s.z, s.w};
    const float aa[4] = {av[r].x, av[r].y, av[r].z, av[r].w};
#pragma unroll
    for (int j = 0; j < 4; ++j) {
      const float e = __expf(se[j]);
      zp[j] += e;
      // off-diag: L = -a -> cheb1 = -a, cheb2 = 2a^2
      float cc = ISK1 ? (-aa[j]) : (2.f * aa[j] * aa[j]);
      if (dchunk) {
        if (pmg * 4 + r == pn4 + j) {  // global m == global n
          const float L = deg[n0 + pn4 + j] - aa[j];
          cc = ISK1 ? L : (2.f * L * L - 1.f);
        }
      }
      pk[r][j] = bf16_rne(e * cc);
    }
  }
#pragma unroll
  for (int j = 0; j < 4; ++j) {
    uint2 v;
    v.x = (unsigned)pk[0][j] | ((unsigned)pk[1][j] << 16);
    v.y = (unsigned)pk[2][j] | ((unsigned)pk[3][j] << 16);
    *(uint2*)&PtDst[(pn4 + j) * LBM + pmg * 4] = v;
  }
}

// grid (32, 2, NB*MS), block 256 (4 waves). kk: 0->cheb1, 1->cheb2.
template <int MS>
__global__ __launch_bounds__(256, 2) void k_main(
    const float* __restrict__ Sall, const float* __restrict__ adj,
    const float* __restrict__ deg, const unsigned short* __restrict__ xT,
    float* __restrict__ rhsP, float* __restrict__ z12P) {
  static_assert(MS == 1 || MS == 2, "MS");
  constexpr int C = 32 / MS;
  __shared__ unsigned short Pt[2][BN * LBM];  // 18432 B, double buffered
  __shared__ float Sraw[BM * BN];             // 16384 B, SINGLE buffer
  __shared__ float Zred[16][BN];              // 4096 B

  // XCD-aware swizzle: dispatch round-robins linear id across 8 XCDs.
  // Give each XCD 4 n-tiles with all (kk,b,ms) -> adj slice (2MB) L2-resident.
  const int flat = blockIdx.x + 32 * (blockIdx.y + 2 * blockIdx.z);
  const int xcd = flat & 7;
  const int jj = flat >> 3;
  const int tile = xcd * 4 + (jj & 3);
  const int rest = jj >> 2;
  const int kk = rest & 1;
  const int t2 = rest >> 1;
  const int ms = t2 % MS;
  const int b = t2 / MS;

  const int n0 = tile * BN, mbase = ms * (C * BM);
  const int t = threadIdx.x, lane = t & 63, w = t >> 6;
  const int ln = lane & 15, quad = lane >> 4;
  const int pn4 = (t & 15) * 4, pmg = t >> 4;
  const float* S = Sall + (size_t)(b * 3 + 1 + kk) * NN * NN;
  const unsigned short* xb = xT + (size_t)b * FT * NN;

  const f32x4 zero4 = {0.f, 0.f, 0.f, 0.f};
  f32x4 acc[4][3];
#pragma unroll
  for (int i = 0; i < 4; ++i)
#pragma unroll
    for (int q = 0; q < 3; ++q) acc[i][q] = zero4;
  float zp[4] = {0.f, 0.f, 0.f, 0.f};

  // staging geometry: wave w owns rows [w*16, w*16+16); one global_load_lds
  // moves 4 rows (64 lanes x 16B = 4 x 256B), LDS dest linear (base+lane*16).
  const int srow = (w << 4) + (lane >> 4);
  const int scol = (lane & 15) << 2;
  float* const lbase = &Sraw[(w << 4) * BN];

  // ---- prologue: stage + pack chunk 0 -> Pt[0]
  {
    const float* g = S + (size_t)(mbase + srow) * NN + n0 + scol;
#pragma unroll
    for (int j2 = 0; j2 < 4; ++j2)
      gload_lds16(g + (size_t)(j2 * 4) * NN, lbase + j2 * 4 * BN);
  }
  float4 av[4];
#pragma unroll
  for (int r = 0; r < 4; ++r)
    av[r] = *(const float4*)(adj + (size_t)(mbase + pmg * 4 + r) * NN + n0 + pn4);
  asm volatile("s_waitcnt vmcnt(0)" ::: "memory");
  __builtin_amdgcn_sched_barrier(0);
  if (kk == 0)
    pack_chunk<true>(Sraw, av, deg, Pt[0], zp, pmg, pn4, mbase == n0, n0);
  else
    pack_chunk<false>(Sraw, av, deg, Pt[0], zp, pmg, pn4, mbase == n0, n0);
  __syncthreads();

  for (int c = 0; c < C; ++c) {
    const int cur = c & 1;
    const bool more = (c + 1 < C);
    const int m0 = mbase + c * BM;

    // 1) B-fragments for chunk c (issue FIRST so their vmcnt wait does not
    //    drain the async staging of chunk c+1)
    short8 bfr[2][3];
#pragma unroll
    for (int ks2 = 0; ks2 < 2; ++ks2)
#pragma unroll
      for (int q = 0; q < 3; ++q)
        bfr[ks2][q] = *(const short8*)(xb + (size_t)(w * 48 + q * 16 + ln) * NN +
                                       m0 + ks2 * 32 + quad * 8);
    __builtin_amdgcn_sched_barrier(0);

    // 2) async-stage chunk c+1 (S -> Sraw) + adj prefetch to regs
    if (more) {
      const int mn = m0 + BM;
      const float* g = S + (size_t)(mn + srow) * NN + n0 + scol;
#pragma unroll
      for (int j2 = 0; j2 < 4; ++j2)
        gload_lds16(g + (size_t)(j2 * 4) * NN, lbase + j2 * 4 * BN);
#pragma unroll
      for (int r = 0; r < 4; ++r)
        av[r] =
            *(const float4*)(adj + (size_t)(mn + pmg * 4 + r) * NN + n0 + pn4);
    }
    __builtin_amdgcn_sched_barrier(0);

    // 3) MFMA chunk c from Pt[cur]
#pragma unroll
    for (int ks2 = 0; ks2 < 2; ++ks2) {
      short8 af[4];
#pragma unroll
      for (int i = 0; i < 4; ++i)
        af[i] = *(const short8*)&Pt[cur][(i * 16 + ln) * LBM + ks2 * 32 +
                                         quad * 8];
#pragma unroll
      for (int i = 0; i < 4; ++i)
#pragma unroll
        for (int q = 0; q < 3; ++q)
          acc[i][q] = __builtin_amdgcn_mfma_f32_16x16x32_bf16(
              af[i], bfr[ks2][q], acc[i][q], 0, 0, 0);
    }

    // 4) pack chunk c+1 -> Pt[cur^1]. Each wave reads only rows IT staged,
    //    so a per-wave vmcnt(0) suffices (no barrier before pack).
    if (more) {
      asm volatile("s_waitcnt vmcnt(0)" ::: "memory");
      __builtin_amdgcn_sched_barrier(0);
      const bool dch = (m0 + BM == n0);
      if (kk == 0)
        pack_chunk<true>(Sraw, av, deg, Pt[cur ^ 1], zp, pmg, pn4, dch, n0);
      else
        pack_chunk<false>(Sraw, av, deg, Pt[cur ^ 1], zp, pmg, pn4, dch, n0);
    }
    __syncthreads();
  }

  // Z reduction
#pragma unroll
  for (int j = 0; j < 4; ++j) Zred[pmg][pn4 + j] = zp[j];
  __syncthreads();
  if (t < 64) {
    float Z = 0.f;
#pragma unroll
    for (int g = 0; g < 16; ++g) Z += Zred[g][t];
    z12P[((size_t)(kk * 8 + b) * MS + ms) * NN + n0 + t] = Z;
  }

  float* outp = rhsP + (((size_t)(kk * 8 + b) * MS + ms) * NN + n0) * FT;
#pragma unroll
  for (int i = 0; i < 4; ++i)
#pragma unroll
    for (int q = 0; q < 3; ++q) {
      const int ft = w * 48 + q * 16 + ln;
#pragma unroll
      for (int r = 0; r < 4; ++r) {
        const int nl = i * 16 + quad * 4 + r;
        outp[(size_t)nl * FT + ft] = acc[i][q][r];
      }
    }
}

// grid (512, 8), block 256: 4 n's per block, thread=(nl=t>>6, o=t&63)
__global__ __launch_bounds__(256) void k_out(
    const float* __restrict__ x, const float* __restrict__ Theta,
    const float* __restrict__ rhsP, const float* __restrict__ z12P,
    const float* __restrict__ z0P, const float* __restrict__ diagE,
    float* __restrict__ out, int MS) {
  __shared__ float xs[4][FT], r1s[4][FT], r2s[4][FT];
  __shared__ float sc[3][4];
  const int b = blockIdx.y, n0 = blockIdx.x * 4;
  const int t = threadIdx.x, o = t & 63, nl = t >> 6;

  for (int l = t; l < 576; l += 256) {
    const int arr = l / 192, idx = l - arr * 192;
    const int row = idx / 48, c4 = (idx % 48) * 4;
    if (arr == 0) {
      *(float4*)&xs[row][c4] =
          *(const float4*)(x + ((size_t)b * NN + n0 + row) * FT + c4);
    } else {
      float4 s = {0.f, 0.f, 0.f, 0.f};
      for (int ms = 0; ms < MS; ++ms) {
        const float4 v = *(const float4*)(rhsP +
            (((size_t)((arr - 1) * 8 + b) * MS + ms) * NN + n0 + row) * FT +
            c4);
        s.x += v.x; s.y += v.y; s.z += v.z; s.w += v.w;
      }
      float* dstbase = (arr == 1) ? &r1s[0][0] : &r2s[0][0];
      *(float4*)(dstbase + row * FT + c4) = s;
    }
  }
  if (t < 12) {
    const int j = t & 3, which = t >> 2;
    float v;
    if (which < 2) {
      float z = 0.f;
      for (int ms = 0; ms < MS; ++ms)
        z += z12P[((size_t)(which * 8 + b) * MS + ms) * NN + n0 + j];
      v = 1.f / z;
    } else {
      float z = 0.f;
      for (int q = 0; q < 2; ++q) z += z0P[((size_t)b * 2 + q) * NN + n0 + j];
      v = diagE[b * NN + n0 + j] / z;
    }
    sc[which][j] = v;
  }
  __syncthreads();

  float a0[12], a1[12], a2[12];
#pragma unroll
  for (int tt = 0; tt < 12; ++tt) a0[tt] = a1[tt] = a2[tt] = 0.f;
#pragma unroll
  for (int f = 0; f < 16; ++f) {
    const float th0 = Theta[(0 * 16 + f) * 64 + o];
    const float th1 = Theta[(1 * 16 + f) * 64 + o];
    const float th2 = Theta[(2 * 16 + f) * 64 + o];
#pragma unroll
    for (int tt = 0; tt < 12; ++tt) {
      a0[tt] += th0 * xs[nl][f * 12 + tt];
      a1[tt] += th1 * r1s[nl][f * 12 + tt];
      a2[tt] += th2 * r2s[nl][f * 12 + tt];
    }
  }
  const float rz1 = sc[0][nl], rz2 = sc[1][nl], c0 = sc[2][nl];
  float r[12];
#pragma unroll
  for (int tt = 0; tt < 12; ++tt)
    r[tt] = fmaxf(a0[tt] * c0 + a1[tt] * rz1 + a2[tt] * rz2, 0.f);
  float4* op4 = (float4*)(out + (((size_t)b * NN + n0 + nl) * 64 + o) * 12);
  op4[0] = make_float4(r[0], r[1], r[2], r[3]);
  op4[1] = make_float4(r[4], r[5], r[6], r[7]);
  op4[2] = make_float4(r[8], r[9], r[10], r[11]);
}

extern "C" void kernel_launch(void* const* d_in, const int* in_sizes, int n_in,
                              void* d_out, int out_size, void* d_ws,
                              size_t ws_size, hipStream_t stream) {
  const float* x = (const float*)d_in[0];
  const float* s_attn = (const float*)d_in[1];
  const float* adj = (const float*)d_in[2];
  const float* Theta = (const float*)d_in[3];
  float* out = (float*)d_out;
  char* ws = (char*)d_ws;

  const size_t szXT = (size_t)NB * FT * NN * 2;   // 6,291,456
  const size_t szDeg = NN * 4;                    // 8,192
  const size_t szZ0 = (size_t)NB * 2 * NN * 4;    // 131,072
  const size_t szDiag = (size_t)NB * NN * 4;      // 65,536
  const size_t base = szXT + szDeg + szZ0 + szDiag;
  const size_t perMS = (size_t)2 * NB * NN * 4          // z12P per split
                       + (size_t)2 * NB * NN * FT * 4;  // rhsP per split

  int MS = 0;
  if (ws_size >= base + 2 * perMS) MS = 2;
  else if (ws_size >= base + 1 * perMS) MS = 1;
  if (MS == 0) return;  // insufficient workspace

  unsigned short* xT = (unsigned short*)ws;
  float* deg = (float*)(ws + szXT);
  float* z0P = (float*)(ws + szXT + szDeg);
  float* diagE = (float*)(ws + szXT + szDeg + szZ0);
  float* z12P = (float*)(ws + base);
  float* rhsP = (float*)(ws + base + (size_t)2 * NB * MS * NN * 4);

  hipLaunchKernelGGL(k_deg, dim3(NN), dim3(256), 0, stream, adj, deg);
  hipLaunchKernelGGL(k_xt, dim3(64, NB), dim3(192), 0, stream, x, xT);
  hipLaunchKernelGGL(k_z0, dim3(32, NB, 2), dim3(256), 0, stream, s_attn, z0P,
                     diagE);
  if (MS == 2) {
    hipLaunchKernelGGL(k_main<2>, dim3(32, 2, NB * 2), dim3(256), 0, stream,
                       s_attn, adj, deg, xT, rhsP, z12P);
  } else {
    hipLaunchKernelGGL(k_main<1>, dim3(32, 2, NB * 1), dim3(256), 0, stream,
                       s_attn, adj, deg, xT, rhsP, z12P);
  }
  hipLaunchKernelGGL(k_out, dim3(512, NB), dim3(256), 0, stream, x, Theta,
                     rhsP, z12P, z0P, diagE, out, MS);
}

// Round 2
// 642.795 us; speedup vs baseline: 1.3852x; 1.0185x over previous
//
#include <hip/hip_runtime.h>

// cheb_conv_aagcn: B=8,K=3,N=2048,F_IN=16,F_OUT=64,T=12
// out[b,n,o,t] = relu( sum_k (1/Z_k[n]) sum_m exp(S[b,k,m,n]) cheb_k[m,n] x[b,m,:] @ Theta_k )
// cheb0=I (diagonal pick), cheb1=L=diag(deg)-adj, cheb2=2L*L-I (elementwise).
//
// v3: FULL FUSION. One block per (tile=32 n-cols, b) handles kk=1,2 over ALL m,
// plus z0/diag capture (S0 direct to regs), plus Theta epilogue + relu.
// Eliminates rhsP/z12P/z0P/diagE workspace round-trip (~300MB) and two kernels.
// Staging: global_load_lds for S1/S2 (spill-free), per-wave row ownership
// (pack needs only per-wave vmcnt(0), one barrier per chunk).
// XCD swizzle: XCD = b -> xT[b] (786KB) L2-resident per XCD.

#define NB 8
#define NN 2048
#define FT 192
#define BN 32
#define BM 64
#define LBM 72  // Pt row stride in bf16 (144B)
#define ZST 33  // Zred padded stride

typedef __attribute__((ext_vector_type(8))) short short8;
typedef __attribute__((ext_vector_type(4))) float f32x4;

__device__ __forceinline__ unsigned short bf16_rne(float f) {
  unsigned u = __float_as_uint(f);
  u += 0x7FFFu + ((u >> 16) & 1u);
  return (unsigned short)(u >> 16);
}

__device__ __forceinline__ void gload_lds16(const float* g, float* l) {
  __builtin_amdgcn_global_load_lds(
      (const __attribute__((address_space(1))) void*)g,
      (__attribute__((address_space(3))) void*)l, 16, 0, 0);
}

__global__ __launch_bounds__(256) void k_deg(const float* __restrict__ adj,
                                             float* __restrict__ deg) {
  const int row = blockIdx.x;
  const float* r = adj + (size_t)row * NN;
  float s = 0.f;
  for (int j = threadIdx.x; j < NN; j += 256) s += r[j];
  for (int off = 32; off; off >>= 1) s += __shfl_down(s, off, 64);
  __shared__ float ls[4];
  if ((threadIdx.x & 63) == 0) ls[threadIdx.x >> 6] = s;
  __syncthreads();
  if (threadIdx.x == 0) deg[row] = ls[0] + ls[1] + ls[2] + ls[3];
}

// grid (64, 8), block 192 (thread = ft). x[b][m][ft] -> xT[b][ft][m] bf16.
__global__ __launch_bounds__(192) void k_xt(const float* __restrict__ x,
                                            unsigned short* __restrict__ xT) {
  const int b = blockIdx.y, m0 = blockIdx.x * 32, ft = threadIdx.x;
  const float* src = x + (size_t)b * NN * FT + ft;
  uint4* dst = (uint4*)(xT + ((size_t)b * FT + ft) * NN + m0);
#pragma unroll
  for (int g = 0; g < 4; ++g) {
    unsigned u[4];
#pragma unroll
    for (int j = 0; j < 4; ++j) {
      float lo = src[(size_t)(m0 + g * 8 + 2 * j) * FT];
      float hi = src[(size_t)(m0 + g * 8 + 2 * j + 1) * FT];
      u[j] = (unsigned)bf16_rne(lo) | ((unsigned)bf16_rne(hi) << 16);
    }
    dst[g] = make_uint4(u[0], u[1], u[2], u[3]);
  }
}

// grid (64, 8) -> (tile, b) via XCD swizzle, block 256 (4 waves).
__global__ __launch_bounds__(256, 2) void k_fused(
    const float* __restrict__ Sall, const float* __restrict__ adj,
    const float* __restrict__ deg, const unsigned short* __restrict__ xT,
    const float* __restrict__ x, const float* __restrict__ Theta,
    float* __restrict__ out) {
  // flat smem, phase-overlaid:
  //  loop:     Sr1[64*32 f32] @0 (8K) | Sr2 @8192 (8K) | Pt[4][32*72 u16] @16384 (18.4K)
  //  epilogue: Zred[3][32][33] f32 @0 (12.7K) -> then
  //            r1s[32*196] @0 (25088B) | r2s @25088 | xs[32*192] @50176 (24576B)
  __shared__ __align__(16) char smem[74752];
  __shared__ float dEs[BN];
  __shared__ float sc[3][BN];

  float* const Sr1 = (float*)smem;
  float* const Sr2 = (float*)(smem + 8192);
  unsigned short* const PtB = (unsigned short*)(smem + 16384);

  // XCD swizzle: dispatch round-robins flat id across 8 XCDs -> XCD = b.
  const int flat = blockIdx.x + (blockIdx.y << 6);
  const int b = flat & 7;
  const int tile = flat >> 3;
  const int n0 = tile * BN;

  const int t = threadIdx.x;
  const int lane = t & 63, w = t >> 6;
  const int ln = lane & 15, quad = lane >> 4;
  // pack geometry: thread owns rows rowg*2, rowg*2+1 x cols col4..col4+3
  const int col4 = (t & 7) << 2;
  const int rowg = t >> 3;  // 0..31
  // staging geometry (within one gload group of 8 rows)
  const int srow = lane >> 3;
  const int scol = (lane & 7) << 2;

  const float* S0 = Sall + (size_t)b * 3 * NN * NN;
  const float* S1 = S0 + (size_t)NN * NN;
  const float* S2 = S1 + (size_t)NN * NN;
  const unsigned short* xb = xT + (size_t)b * FT * NN;

  const int cdiag = n0 >> 6;  // the one chunk containing diagonal elements
  const float4 dgv = *(const float4*)(deg + n0 + col4);

  const f32x4 zero4 = {0.f, 0.f, 0.f, 0.f};
  f32x4 acc1[2][3], acc2[2][3];
#pragma unroll
  for (int i = 0; i < 2; ++i)
#pragma unroll
    for (int q = 0; q < 3; ++q) {
      acc1[i][q] = zero4;
      acc2[i][q] = zero4;
    }
  float zp0[4] = {0.f, 0.f, 0.f, 0.f};
  float zp1[4] = {0.f, 0.f, 0.f, 0.f};
  float zp2[4] = {0.f, 0.f, 0.f, 0.f};

  auto STAGE = [&](int c) {
    const int m0s = c * BM;
#pragma unroll
    for (int j2 = 0; j2 < 2; ++j2) {
      const int r0 = (w << 4) + (j2 << 3);
      const size_t go = (size_t)(m0s + r0 + srow) * NN + n0 + scol;
      gload_lds16(S1 + go, Sr1 + r0 * BN);
      gload_lds16(S2 + go, Sr2 + r0 * BN);
    }
  };

  auto LOADAV = [&](int c, float4 av[2], float4 sv[2]) {
#pragma unroll
    for (int r = 0; r < 2; ++r) {
      const int gm = c * BM + rowg * 2 + r;
      av[r] = *(const float4*)(adj + (size_t)gm * NN + n0 + col4);
      sv[r] = *(const float4*)(S0 + (size_t)gm * NN + n0 + col4);
    }
  };

  auto PACK = [&](int c, int buf, const float4 av[2], const float4 sv[2]) {
    const bool isd = (c == cdiag);
    unsigned short* P1 = PtB + (size_t)buf * 2304;
    unsigned short* P2 = PtB + (size_t)(2 + buf) * 2304;
    unsigned short q1[2][4], q2[2][4];
    const float dg[4] = {dgv.x, dgv.y, dgv.z, dgv.w};
#pragma unroll
    for (int r = 0; r < 2; ++r) {
      const int lrow = rowg * 2 + r;
      const float4 s1 = *(const float4*)&Sr1[lrow * BN + col4];
      const float4 s2 = *(const float4*)&Sr2[lrow * BN + col4];
      const float se1[4] = {s1.x, s1.y, s1.z, s1.w};
      const float se2[4] = {s2.x, s2.y, s2.z, s2.w};
      const float aa[4] = {av[r].x, av[r].y, av[r].z, av[r].w};
      const float s0e[4] = {sv[r].x, sv[r].y, sv[r].z, sv[r].w};
#pragma unroll
      for (int j = 0; j < 4; ++j) {
        const float e0 = __expf(s0e[j]);
        const float e1 = __expf(se1[j]);
        const float e2 = __expf(se2[j]);
        zp0[j] += e0;
        zp1[j] += e1;
        zp2[j] += e2;
        float c1 = -aa[j];
        float c2 = 2.f * aa[j] * aa[j];
        if (isd) {
          if (c * BM + lrow == n0 + col4 + j) {
            const float L = dg[j] - aa[j];
            c1 = L;
            c2 = 2.f * L * L - 1.f;
            dEs[col4 + j] = e0;
          }
        }
        q1[r][j] = bf16_rne(e1 * c1);
        q2[r][j] = bf16_rne(e2 * c2);
      }
    }
#pragma unroll
    for (int j = 0; j < 4; ++j) {
      const unsigned v1 = (unsigned)q1[0][j] | ((unsigned)q1[1][j] << 16);
      const unsigned v2 = (unsigned)q2[0][j] | ((unsigned)q2[1][j] << 16);
      *(unsigned*)&P1[(col4 + j) * LBM + rowg * 2] = v1;
      *(unsigned*)&P2[(col4 + j) * LBM + rowg * 2] = v2;
    }
  };

  // ---- prologue: stage + pack chunk 0
  STAGE(0);
  {
    float4 av[2], sv[2];
    LOADAV(0, av, sv);
    asm volatile("s_waitcnt vmcnt(0)" ::: "memory");
    __builtin_amdgcn_sched_barrier(0);
    PACK(0, 0, av, sv);
  }
  __syncthreads();

  for (int c = 0; c < 32; ++c) {
    const int buf = c & 1;
    const bool more = (c < 31);
    const int m0 = c * BM;

    // 1) B-fragments for chunk c (shared by both kk) -- issue first
    short8 bfr[2][3];
#pragma unroll
    for (int ks2 = 0; ks2 < 2; ++ks2)
#pragma unroll
      for (int q = 0; q < 3; ++q)
        bfr[ks2][q] = *(const short8*)(xb +
            (size_t)(w * 48 + q * 16 + ln) * NN + m0 + ks2 * 32 + quad * 8);
    __builtin_amdgcn_sched_barrier(0);

    // 2) async-stage chunk c+1 + adj/S0 reg prefetch
    float4 avn[2], svn[2];
    if (more) {
      STAGE(c + 1);
      LOADAV(c + 1, avn, svn);
    }
    __builtin_amdgcn_sched_barrier(0);

    // 3) MFMA chunk c for both kk from Pt[buf]
#pragma unroll
    for (int ks2 = 0; ks2 < 2; ++ks2) {
      short8 a1[2], a2[2];
#pragma unroll
      for (int i = 0; i < 2; ++i) {
        a1[i] = *(const short8*)&PtB[(size_t)buf * 2304 + (i * 16 + ln) * LBM +
                                     ks2 * 32 + quad * 8];
        a2[i] = *(const short8*)&PtB[(size_t)(2 + buf) * 2304 +
                                     (i * 16 + ln) * LBM + ks2 * 32 + quad * 8];
      }
#pragma unroll
      for (int i = 0; i < 2; ++i)
#pragma unroll
        for (int q = 0; q < 3; ++q) {
          acc1[i][q] = __builtin_amdgcn_mfma_f32_16x16x32_bf16(
              a1[i], bfr[ks2][q], acc1[i][q], 0, 0, 0);
          acc2[i][q] = __builtin_amdgcn_mfma_f32_16x16x32_bf16(
              a2[i], bfr[ks2][q], acc2[i][q], 0, 0, 0);
        }
    }

    // 4) pack chunk c+1 (own-wave rows only -> per-wave vmcnt(0) suffices)
    if (more) {
      asm volatile("s_waitcnt vmcnt(0)" ::: "memory");
      __builtin_amdgcn_sched_barrier(0);
      PACK(c + 1, buf ^ 1, avn, svn);
    }
    __syncthreads();
  }

  // ---- Z reductions (overlay Zred onto Sr region; Pt/Sr dead) ----
  float* Zr = (float*)smem;  // [3][32][ZST]
#pragma unroll
  for (int j = 0; j < 4; ++j) {
    Zr[0 * 32 * ZST + rowg * ZST + col4 + j] = zp0[j];
    Zr[1 * 32 * ZST + rowg * ZST + col4 + j] = zp1[j];
    Zr[2 * 32 * ZST + rowg * ZST + col4 + j] = zp2[j];
  }
  __syncthreads();
  if (t < 96) {
    const int which = t >> 5, n = t & 31;
    float Z = 0.f;
#pragma unroll
    for (int g = 0; g < 32; ++g) Z += Zr[which * 32 * ZST + g * ZST + n];
    sc[which][n] = (which == 0) ? (dEs[n] / Z) : (1.f / Z);
  }
  __syncthreads();

  // ---- stage rhs (raw acc) + x rows into LDS ----
  float* const r1s = (float*)smem;            // [32][196]
  float* const r2s = (float*)(smem + 25088);  // [32][196]
  float* const xs = (float*)(smem + 50176);   // [32][192]
#pragma unroll
  for (int i = 0; i < 2; ++i)
#pragma unroll
    for (int q = 0; q < 3; ++q) {
      const int ft = w * 48 + q * 16 + ln;
#pragma unroll
      for (int r = 0; r < 4; ++r) {
        const int nl = i * 16 + quad * 4 + r;
        r1s[nl * 196 + ft] = acc1[i][q][r];
        r2s[nl * 196 + ft] = acc2[i][q][r];
      }
    }
  for (int l = t; l < 32 * 48; l += 256) {
    const int row = l / 48, c4 = (l % 48) * 4;
    *(float4*)&xs[row * 192 + c4] =
        *(const float4*)(x + ((size_t)b * NN + n0 + row) * FT + c4);
  }
  __syncthreads();

  // ---- epilogue: out[n,o,t] = relu(c0*x@Th0 + rz1*rhs1@Th1 + rz2*rhs2@Th2)
  const int o = t & 63, nl2 = t >> 6;
  float th0[16], th1[16], th2[16];
#pragma unroll
  for (int f = 0; f < 16; ++f) {
    th0[f] = Theta[f * 64 + o];
    th1[f] = Theta[(16 + f) * 64 + o];
    th2[f] = Theta[(32 + f) * 64 + o];
  }
#pragma unroll 1
  for (int ni = 0; ni < 8; ++ni) {
    const int n = ni * 4 + nl2;
    float a0[12], a1[12], a2[12];
#pragma unroll
    for (int e = 0; e < 12; ++e) a0[e] = a1[e] = a2[e] = 0.f;
#pragma unroll
    for (int f = 0; f < 16; ++f) {
      const f32x4* xv = (const f32x4*)&xs[n * 192 + f * 12];
      const f32x4* r1v = (const f32x4*)&r1s[n * 196 + f * 12];
      const f32x4* r2v = (const f32x4*)&r2s[n * 196 + f * 12];
#pragma unroll
      for (int g = 0; g < 3; ++g)
#pragma unroll
        for (int e = 0; e < 4; ++e) {
          a0[g * 4 + e] += th0[f] * xv[g][e];
          a1[g * 4 + e] += th1[f] * r1v[g][e];
          a2[g * 4 + e] += th2[f] * r2v[g][e];
        }
    }
    const float c0 = sc[0][n], rz1 = sc[1][n], rz2 = sc[2][n];
    float4* op = (float4*)(out + (((size_t)b * NN + n0 + n) * 64 + o) * 12);
#pragma unroll
    for (int g = 0; g < 3; ++g) {
      float4 rv;
      rv.x = fmaxf(a0[g * 4 + 0] * c0 + a1[g * 4 + 0] * rz1 + a2[g * 4 + 0] * rz2, 0.f);
      rv.y = fmaxf(a0[g * 4 + 1] * c0 + a1[g * 4 + 1] * rz1 + a2[g * 4 + 1] * rz2, 0.f);
      rv.z = fmaxf(a0[g * 4 + 2] * c0 + a1[g * 4 + 2] * rz1 + a2[g * 4 + 2] * rz2, 0.f);
      rv.w = fmaxf(a0[g * 4 + 3] * c0 + a1[g * 4 + 3] * rz1 + a2[g * 4 + 3] * rz2, 0.f);
      op[g] = rv;
    }
  }
}

extern "C" void kernel_launch(void* const* d_in, const int* in_sizes, int n_in,
                              void* d_out, int out_size, void* d_ws,
                              size_t ws_size, hipStream_t stream) {
  (void)in_sizes;
  (void)n_in;
  (void)out_size;
  const float* x = (const float*)d_in[0];
  const float* s_attn = (const float*)d_in[1];
  const float* adj = (const float*)d_in[2];
  const float* Theta = (const float*)d_in[3];
  float* out = (float*)d_out;
  char* ws = (char*)d_ws;

  const size_t szXT = (size_t)NB * FT * NN * 2;  // 6,291,456
  const size_t szDeg = NN * 4;                   // 8,192
  if (ws_size < szXT + szDeg) return;

  unsigned short* xT = (unsigned short*)ws;
  float* deg = (float*)(ws + szXT);

  hipLaunchKernelGGL(k_deg, dim3(NN), dim3(256), 0, stream, adj, deg);
  hipLaunchKernelGGL(k_xt, dim3(64, NB), dim3(192), 0, stream, x, xT);
  hipLaunchKernelGGL(k_fused, dim3(64, NB), dim3(256), 0, stream, s_attn, adj,
                     deg, xT, x, Theta, out);
}